// Round 19
// baseline (112.865 us; speedup 1.0000x reference)
//
#include <hip/hip_runtime.h>
#include <math.h>

// Problem constants
#define BB 16384
#define TT 99
#define RR 10
#define LL 3

// DPP cross-lane (VALU pipe):
// QP(v,j): every lane of a 4-lane quad gets quad-lane j's value.
// HMIR(v): mirror within each 8-lane half-row (lane g <-> 7-g).
#define QP(v, j) __int_as_float(__builtin_amdgcn_mov_dpp(                     \
    __float_as_int(v), (j) * 0x55, 0xF, 0xF, true))
#define HMIR(v)  __int_as_float(__builtin_amdgcn_mov_dpp(                     \
    __float_as_int(v), 0x141, 0xF, 0xF, true))

// One 32-step (or 3-step tail) section of the recurrence: pure register loop.
// TB/N compile-time -> store offsets fold into 13-bit immediates.
// R19: tanh PAIR with shared rcp -- 3 trans/step instead of 4:
//   r = rcp((eA+1)(eB+1));  tanhA = 1-2(eB+1)r;  tanhB = 1-2(eA+1)r.
template <int TB, int N>
__device__ __forceinline__ void rnn_section(
    uint64_t wq, float& hoA, float& hoB,
    const float (&UA)[RR], const float (&UB)[RR],
    float cA1, float cA2, float cB1, float cB2,
    float* __restrict__ outA, float* __restrict__ outB)
{
#pragma unroll
    for (int u = 0; u < N; ++u) {
        const int sel = (int)(wq & 3);
        wq >>= 2;

        // gather full h: 11 DPP ops (VALU pipe, zero memory)
        float hg[RR];
        hg[0] = QP(hoA, 0); hg[1] = QP(hoA, 1);
        hg[2] = QP(hoA, 2); hg[3] = QP(hoA, 3);
        const float mr = HMIR(hoA);
        hg[4] = QP(mr, 0);  hg[5] = QP(mr, 1);
        hg[6] = QP(mr, 2);  hg[7] = QP(mr, 3);
        hg[8] = QP(hoB, 0); hg[9] = QP(hoB, 1);

        const bool is1 = (sel == 1);
        float aA0 = is1 ? cA1 : cA2, aB0 = is1 ? cB1 : cB2;
        float aA1 = 0.0f, aB1 = 0.0f;
#pragma unroll
        for (int i = 0; i < 5; ++i) {          // split chains: 2x5 FMA deep
            aA0 = fmaf(hg[i],     UA[i],     aA0);
            aA1 = fmaf(hg[5 + i], UA[5 + i], aA1);
            aB0 = fmaf(hg[i],     UB[i],     aB0);
            aB1 = fmaf(hg[5 + i], UB[5 + i], aB1);
        }
        // tanh pair, shared rcp (3 trans: 2 exp + 1 rcp)
        const float eA = __expf(2.0f * (aA0 + aA1));
        const float eB = __expf(2.0f * (aB0 + aB1));
        const float pA = eA + 1.0f, pB = eB + 1.0f;
        const float r  = __builtin_amdgcn_rcpf(pA * pB);
        const float hnA = fmaf(-2.0f * pB, r, 1.0f);   // 1 - 2/pA
        const float hnB = fmaf(-2.0f * pA, r, 1.0f);   // 1 - 2/pB
        if (sel != 0) { hoA = hnA; hoB = hnB; }   // Keras masking: carry h

        // direct stores, compile-time offsets (max (TB+u)*40B = 3920 < 4096)
        outA[(TB + u) * RR] = hoA;
        outB[(TB + u) * RR] = hoB;
    }
}

// ===================== K1: recurrence -> states (direct) =====================
// Zero memory ops in the sequential loop (2-bit token codes packed in four
// u64 registers). Grid 512x256 = 2048 waves = 8 waves/CU.
// Also zeroes the K2 last-block counter each launch (replay-safe).
__global__ __launch_bounds__(256, 2)
void rnn_seq_kernel(const int* __restrict__ tok_ids,
                    const float* __restrict__ emb,
                    const float* __restrict__ W,
                    const float* __restrict__ U,
                    const float* __restrict__ bvec,
                    float* __restrict__ states_out,
                    int* __restrict__ counter)
{
    __shared__ unsigned char s_tk[4][8 * 100];   // 3.2 KB: token byte per (row,t)

    const int tid = threadIdx.x;
    const int w   = tid >> 6;
    const int l   = tid & 63;
    const int r8  = l >> 3;                   // row within wave (0..7)
    const int g   = l & 7;                    // unit slot (0..7)
    const int rowbase = blockIdx.x * 32 + w * 8;

    if (blockIdx.x == 0 && tid == 0) *counter = 0;   // reset K2 gate each launch

    // ---- stage tokens (coalesced) ----
#pragma unroll
    for (int i = 0; i < 13; ++i) {
        const int p = l + 64 * i;
        if (p < 8 * TT) {
            const int r = p / TT;             // compile-time divisor
            s_tk[w][r * 100 + (p - r * TT)] =
                (unsigned char)tok_ids[(size_t)rowbase * TT + p];
        }
    }

    // ---- pack own row's 99 token codes into 4 u64 registers (2 bits/step) ----
    const uint32_t* tp = reinterpret_cast<const uint32_t*>(&s_tk[w][r8 * 100]);
    uint64_t w0 = 0, w1 = 0, w2 = 0, w3 = 0;
#pragma unroll
    for (int t = 0; t < 32; ++t)
        w0 |= (uint64_t)((tp[t >> 2] >> (8 * (t & 3))) & 3) << (2 * t);
#pragma unroll
    for (int t = 32; t < 64; ++t)
        w1 |= (uint64_t)((tp[t >> 2] >> (8 * (t & 3))) & 3) << (2 * (t - 32));
#pragma unroll
    for (int t = 64; t < 96; ++t)
        w2 |= (uint64_t)((tp[t >> 2] >> (8 * (t & 3))) & 3) << (2 * (t - 64));
#pragma unroll
    for (int t = 96; t < 99; ++t)
        w3 |= (uint64_t)((tp[t >> 2] >> (8 * (t & 3))) & 3) << (2 * (t - 96));

    // ---- per-lane gather order (quad-dependent) + weight coefficients ----
    const int qpar = g >> 2;
    int ord[8];
#pragma unroll
    for (int j = 0; j < 4; ++j) {
        ord[j]     = qpar ? 4 + j : j;
        ord[4 + j] = qpar ? 3 - j : 7 - j;
    }
    const int jA = g;
    const int jB = ((g & 3) < 2) ? 8 + (g & 3) : 8;

    float UA[RR], UB[RR];
#pragma unroll
    for (int k2 = 0; k2 < 8; ++k2) {
        UA[k2] = U[ord[k2] * RR + jA];
        UB[k2] = U[ord[k2] * RR + jB];
    }
    UA[8] = U[8 * RR + jA]; UA[9] = U[9 * RR + jA];
    UB[8] = U[8 * RR + jB]; UB[9] = U[9 * RR + jB];

    float cA1 = bvec[jA], cA2 = cA1, cB1 = bvec[jB], cB2 = cB1;
#pragma unroll
    for (int i = 0; i < RR; ++i) {
        const float e1 = emb[RR + i];          // token-1 row
        const float e2 = emb[2 * RR + i];      // token-2 row
        const float wA = W[i * RR + jA];
        const float wB = W[i * RR + jB];
        cA1 = fmaf(e1, wA, cA1); cA2 = fmaf(e2, wA, cA2);
        cB1 = fmaf(e1, wB, cB1); cB2 = fmaf(e2, wB, cB2);
    }

    float hoA = 0.0f, hoB = 0.0f;
    float* outA = states_out + (size_t)(rowbase + r8) * (TT * RR) + jA;
    float* outB = states_out + (size_t)(rowbase + r8) * (TT * RR) + jB;

    rnn_section< 0, 32>(w0, hoA, hoB, UA, UB, cA1, cA2, cB1, cB2, outA, outB);
    rnn_section<32, 32>(w1, hoA, hoB, UA, UB, cA1, cA2, cB1, cB2, outA, outB);
    rnn_section<64, 32>(w2, hoA, hoB, UA, UB, cA1, cA2, cB1, cB2, outA, outB);
    rnn_section<96,  3>(w3, hoA, hoB, UA, UB, cA1, cA2, cB1, cB2, outA, outB);
}

// ============== K2: epilogue (full occupancy) + last-block finalize ==============
__global__ __launch_bounds__(256)
void epilogue_kernel(const float* __restrict__ states,
                     const float* __restrict__ labels,
                     const float* __restrict__ Wo,
                     const float* __restrict__ bo,
                     float* __restrict__ probs_out,
                     float* __restrict__ ws,
                     int* __restrict__ counter,
                     float* __restrict__ out_tail)
{
    const int NT     = BB * TT;               // 1,622,016
    const int tid    = blockIdx.x * 256 + threadIdx.x;
    const int stride = 2048 * 256;

    float Wc0[RR], Wc1[RR], Wc2[RR];
#pragma unroll
    for (int j = 0; j < RR; ++j) {
        Wc0[j] = Wo[j * LL + 0];
        Wc1[j] = Wo[j * LL + 1];
        Wc2[j] = Wo[j * LL + 2];
    }
    const float b0 = bo[0], b1 = bo[1], b2 = bo[2];

    float loss = 0.0f;
    int   corr = 0;

#pragma unroll 1
    for (int idx = tid; idx < NT; idx += stride) {
        const float* hp = states + (size_t)idx * RR;   // 8B-aligned (40B stride)
        float h[RR];
#pragma unroll
        for (int j = 0; j < RR; j += 2) {
            const float2 v = *reinterpret_cast<const float2*>(hp + j);
            h[j] = v.x; h[j + 1] = v.y;
        }
        const float la1 = labels[(size_t)idx * LL + 1];
        const float la2 = labels[(size_t)idx * LL + 2];
        const int   y   = (la1 > 0.5f) ? 1 : ((la2 > 0.5f) ? 2 : 0);

        float l0 = b0, l1 = b1, l2 = b2;
#pragma unroll
        for (int j = 0; j < RR; ++j) {
            l0 = fmaf(h[j], Wc0[j], l0);
            l1 = fmaf(h[j], Wc1[j], l1);
            l2 = fmaf(h[j], Wc2[j], l2);
        }
        const float e0 = __expf(l0), e1 = __expf(l1), e2 = __expf(l2);
        const float S  = e0 + e1 + e2;
        const float rs = __builtin_amdgcn_rcpf(S);
        probs_out[(size_t)idx * LL + 0] = e0 * rs;
        probs_out[(size_t)idx * LL + 1] = e1 * rs;
        probs_out[(size_t)idx * LL + 2] = e2 * rs;

        // loss: -log(clip(p_y, 1e-7, 1)) == min(logS - l_y, -log(1e-7))
        const float ly = (y == 0) ? l0 : ((y == 1) ? l1 : l2);
        loss += fminf(__logf(S) - ly, 16.11809565f);

        // accuracy: argmax(logits) == argmax(probs) (monotonic, same ties)
        int ap = 0; float pm = l0;
        if (l1 > pm) { ap = 1; pm = l1; }
        if (l2 > pm) { ap = 2; }
        corr += (ap == y) ? 1 : 0;
    }

    // block reduction -> one partial pair per block (deterministic)
    __shared__ float sl[4], sc[4];
    __shared__ bool  amLast;
    float ls = loss, cs = (float)corr;
#pragma unroll
    for (int off = 32; off > 0; off >>= 1) {
        ls += __shfl_down(ls, off, 64);
        cs += __shfl_down(cs, off, 64);
    }
    if ((threadIdx.x & 63) == 0) { sl[threadIdx.x >> 6] = ls; sc[threadIdx.x >> 6] = cs; }
    __syncthreads();
    if (threadIdx.x == 0) {
        ws[blockIdx.x]        = sl[0] + sl[1] + sl[2] + sl[3];
        ws[2048 + blockIdx.x] = sc[0] + sc[1] + sc[2] + sc[3];
        __threadfence();                      // publish partials (device scope)
        const int old = atomicAdd(counter, 1);
        amLast = (old == 2047);
    }
    __syncthreads();

    // ---- last arriving block: fixed-order final reduce (deterministic) ----
    if (amLast) {
        const int t = threadIdx.x;
        float fl = 0.0f, fc = 0.0f;
#pragma unroll
        for (int i = 0; i < 8; ++i) {
            fl += ws[t + 256 * i];
            fc += ws[2048 + t + 256 * i];
        }
#pragma unroll
        for (int off = 32; off > 0; off >>= 1) {
            fl += __shfl_down(fl, off, 64);
            fc += __shfl_down(fc, off, 64);
        }
        if ((t & 63) == 0) { sl[t >> 6] = fl; sc[t >> 6] = fc; }
        __syncthreads();
        if (t == 0) {
            const float L = sl[0] + sl[1] + sl[2] + sl[3];
            const float C = sc[0] + sc[1] + sc[2] + sc[3];
            const float inv = 1.0f / (float)((size_t)BB * TT);
            out_tail[0] = C * inv;   // accuracy
            out_tail[1] = L * inv;   // loss
        }
    }
}

extern "C" void kernel_launch(void* const* d_in, const int* in_sizes, int n_in,
                              void* d_out, int out_size, void* d_ws, size_t ws_size,
                              hipStream_t stream)
{
    const int*   tok    = (const int*)  d_in[0];
    const float* labels = (const float*)d_in[1];
    // d_in[2] = mask (unused by reference math)
    const float* emb = (const float*)d_in[3];
    const float* W   = (const float*)d_in[4];
    const float* U   = (const float*)d_in[5];
    const float* bv  = (const float*)d_in[6];
    const float* Wo  = (const float*)d_in[7];
    const float* bo  = (const float*)d_in[8];

    float* out    = (float*)d_out;
    float* states = out;                                  // [B,T,10]
    float* probs  = out + (size_t)BB * TT * RR;           // [B,T,3]
    float* tail   = out + (size_t)BB * TT * (RR + LL);    // accuracy, loss
    float* ws     = (float*)d_ws;                         // 4096 floats + 1 int
    int*   cnt    = (int*)(ws + 4096);

    rnn_seq_kernel<<<512, 256, 0, stream>>>(tok, emb, W, U, bv, states, cnt);
    epilogue_kernel<<<2048, 256, 0, stream>>>(states, labels, Wo, bo, probs,
                                              ws, cnt, tail);
}

// Round 20
// 49.485 us; speedup vs baseline: 2.2808x; 2.2808x over previous
//
#include <hip/hip_runtime.h>
#include <math.h>

// Problem constants
#define BB 16384
#define TT 99
#define RR 10
#define LL 3

// DPP cross-lane (VALU pipe):
// QP(v,j): every lane of a 4-lane quad gets quad-lane j's value.
// HMIR(v): mirror within each 8-lane half-row (lane g <-> 7-g).
#define QP(v, j) __int_as_float(__builtin_amdgcn_mov_dpp(                     \
    __float_as_int(v), (j) * 0x55, 0xF, 0xF, true))
#define HMIR(v)  __int_as_float(__builtin_amdgcn_mov_dpp(                     \
    __float_as_int(v), 0x141, 0xF, 0xF, true))

// One 32-step (or 3-step tail) section of the recurrence: pure register loop.
// TB/N compile-time -> store offsets fold into 13-bit immediates.
// tanh PAIR with shared rcp -- 3 trans/step instead of 4 (verified R19):
//   r = rcp((eA+1)(eB+1));  tanhA = 1-2(eB+1)r;  tanhB = 1-2(eA+1)r.
template <int TB, int N>
__device__ __forceinline__ void rnn_section(
    uint64_t wq, float& hoA, float& hoB,
    const float (&UA)[RR], const float (&UB)[RR],
    float cA1, float cA2, float cB1, float cB2,
    float* __restrict__ outA, float* __restrict__ outB)
{
#pragma unroll
    for (int u = 0; u < N; ++u) {
        const int sel = (int)(wq & 3);
        wq >>= 2;

        // gather full h: 11 DPP ops (VALU pipe, zero memory)
        float hg[RR];
        hg[0] = QP(hoA, 0); hg[1] = QP(hoA, 1);
        hg[2] = QP(hoA, 2); hg[3] = QP(hoA, 3);
        const float mr = HMIR(hoA);
        hg[4] = QP(mr, 0);  hg[5] = QP(mr, 1);
        hg[6] = QP(mr, 2);  hg[7] = QP(mr, 3);
        hg[8] = QP(hoB, 0); hg[9] = QP(hoB, 1);

        const bool is1 = (sel == 1);
        float aA0 = is1 ? cA1 : cA2, aB0 = is1 ? cB1 : cB2;
        float aA1 = 0.0f, aB1 = 0.0f;
#pragma unroll
        for (int i = 0; i < 5; ++i) {          // split chains: 2x5 FMA deep
            aA0 = fmaf(hg[i],     UA[i],     aA0);
            aA1 = fmaf(hg[5 + i], UA[5 + i], aA1);
            aB0 = fmaf(hg[i],     UB[i],     aB0);
            aB1 = fmaf(hg[5 + i], UB[5 + i], aB1);
        }
        // tanh pair, shared rcp (3 trans: 2 exp + 1 rcp)
        const float eA = __expf(2.0f * (aA0 + aA1));
        const float eB = __expf(2.0f * (aB0 + aB1));
        const float pA = eA + 1.0f, pB = eB + 1.0f;
        const float r  = __builtin_amdgcn_rcpf(pA * pB);
        const float hnA = fmaf(-2.0f * pB, r, 1.0f);   // 1 - 2/pA
        const float hnB = fmaf(-2.0f * pA, r, 1.0f);   // 1 - 2/pB
        if (sel != 0) { hoA = hnA; hoB = hnB; }   // Keras masking: carry h

        // direct stores, compile-time offsets (max (TB+u)*40B = 3920 < 4096)
        outA[(TB + u) * RR] = hoA;
        outB[(TB + u) * RR] = hoB;
    }
}

// ===================== K1: recurrence -> states (direct) =====================
// Zero memory ops in the sequential loop (2-bit token codes packed in four
// u64 registers). Grid 512x256 = 2048 waves = 8 waves/CU.
__global__ __launch_bounds__(256, 2)
void rnn_seq_kernel(const int* __restrict__ tok_ids,
                    const float* __restrict__ emb,
                    const float* __restrict__ W,
                    const float* __restrict__ U,
                    const float* __restrict__ bvec,
                    float* __restrict__ states_out)
{
    __shared__ unsigned char s_tk[4][8 * 100];   // 3.2 KB: token byte per (row,t)

    const int tid = threadIdx.x;
    const int w   = tid >> 6;
    const int l   = tid & 63;
    const int r8  = l >> 3;                   // row within wave (0..7)
    const int g   = l & 7;                    // unit slot (0..7)
    const int rowbase = blockIdx.x * 32 + w * 8;

    // ---- stage tokens (coalesced) ----
#pragma unroll
    for (int i = 0; i < 13; ++i) {
        const int p = l + 64 * i;
        if (p < 8 * TT) {
            const int r = p / TT;             // compile-time divisor
            s_tk[w][r * 100 + (p - r * TT)] =
                (unsigned char)tok_ids[(size_t)rowbase * TT + p];
        }
    }

    // ---- pack own row's 99 token codes into 4 u64 registers (2 bits/step) ----
    const uint32_t* tp = reinterpret_cast<const uint32_t*>(&s_tk[w][r8 * 100]);
    uint64_t w0 = 0, w1 = 0, w2 = 0, w3 = 0;
#pragma unroll
    for (int t = 0; t < 32; ++t)
        w0 |= (uint64_t)((tp[t >> 2] >> (8 * (t & 3))) & 3) << (2 * t);
#pragma unroll
    for (int t = 32; t < 64; ++t)
        w1 |= (uint64_t)((tp[t >> 2] >> (8 * (t & 3))) & 3) << (2 * (t - 32));
#pragma unroll
    for (int t = 64; t < 96; ++t)
        w2 |= (uint64_t)((tp[t >> 2] >> (8 * (t & 3))) & 3) << (2 * (t - 64));
#pragma unroll
    for (int t = 96; t < 99; ++t)
        w3 |= (uint64_t)((tp[t >> 2] >> (8 * (t & 3))) & 3) << (2 * (t - 96));

    // ---- per-lane gather order (quad-dependent) + weight coefficients ----
    const int qpar = g >> 2;
    int ord[8];
#pragma unroll
    for (int j = 0; j < 4; ++j) {
        ord[j]     = qpar ? 4 + j : j;
        ord[4 + j] = qpar ? 3 - j : 7 - j;
    }
    const int jA = g;
    const int jB = ((g & 3) < 2) ? 8 + (g & 3) : 8;

    float UA[RR], UB[RR];
#pragma unroll
    for (int k2 = 0; k2 < 8; ++k2) {
        UA[k2] = U[ord[k2] * RR + jA];
        UB[k2] = U[ord[k2] * RR + jB];
    }
    UA[8] = U[8 * RR + jA]; UA[9] = U[9 * RR + jA];
    UB[8] = U[8 * RR + jB]; UB[9] = U[9 * RR + jB];

    float cA1 = bvec[jA], cA2 = cA1, cB1 = bvec[jB], cB2 = cB1;
#pragma unroll
    for (int i = 0; i < RR; ++i) {
        const float e1 = emb[RR + i];          // token-1 row
        const float e2 = emb[2 * RR + i];      // token-2 row
        const float wA = W[i * RR + jA];
        const float wB = W[i * RR + jB];
        cA1 = fmaf(e1, wA, cA1); cA2 = fmaf(e2, wA, cA2);
        cB1 = fmaf(e1, wB, cB1); cB2 = fmaf(e2, wB, cB2);
    }

    float hoA = 0.0f, hoB = 0.0f;
    float* outA = states_out + (size_t)(rowbase + r8) * (TT * RR) + jA;
    float* outB = states_out + (size_t)(rowbase + r8) * (TT * RR) + jB;

    rnn_section< 0, 32>(w0, hoA, hoB, UA, UB, cA1, cA2, cB1, cB2, outA, outB);
    rnn_section<32, 32>(w1, hoA, hoB, UA, UB, cA1, cA2, cB1, cB2, outA, outB);
    rnn_section<64, 32>(w2, hoA, hoB, UA, UB, cA1, cA2, cB1, cB2, outA, outB);
    rnn_section<96,  3>(w3, hoA, hoB, UA, UB, cA1, cA2, cB1, cB2, outA, outB);
}

// ===================== K2: epilogue (full occupancy) =====================
__global__ __launch_bounds__(256)
void epilogue_kernel(const float* __restrict__ states,
                     const float* __restrict__ labels,
                     const float* __restrict__ Wo,
                     const float* __restrict__ bo,
                     float* __restrict__ probs_out,
                     float* __restrict__ ws)
{
    const int NT     = BB * TT;               // 1,622,016
    const int tid    = blockIdx.x * 256 + threadIdx.x;
    const int stride = 2048 * 256;

    float Wc0[RR], Wc1[RR], Wc2[RR];
#pragma unroll
    for (int j = 0; j < RR; ++j) {
        Wc0[j] = Wo[j * LL + 0];
        Wc1[j] = Wo[j * LL + 1];
        Wc2[j] = Wo[j * LL + 2];
    }
    const float b0 = bo[0], b1 = bo[1], b2 = bo[2];

    float loss = 0.0f;
    int   corr = 0;

#pragma unroll 1
    for (int idx = tid; idx < NT; idx += stride) {
        const float* hp = states + (size_t)idx * RR;   // 8B-aligned (40B stride)
        float h[RR];
#pragma unroll
        for (int j = 0; j < RR; j += 2) {
            const float2 v = *reinterpret_cast<const float2*>(hp + j);
            h[j] = v.x; h[j + 1] = v.y;
        }
        const float la1 = labels[(size_t)idx * LL + 1];
        const float la2 = labels[(size_t)idx * LL + 2];
        const int   y   = (la1 > 0.5f) ? 1 : ((la2 > 0.5f) ? 2 : 0);

        float l0 = b0, l1 = b1, l2 = b2;
#pragma unroll
        for (int j = 0; j < RR; ++j) {
            l0 = fmaf(h[j], Wc0[j], l0);
            l1 = fmaf(h[j], Wc1[j], l1);
            l2 = fmaf(h[j], Wc2[j], l2);
        }
        const float e0 = __expf(l0), e1 = __expf(l1), e2 = __expf(l2);
        const float S  = e0 + e1 + e2;
        const float rs = __builtin_amdgcn_rcpf(S);
        probs_out[(size_t)idx * LL + 0] = e0 * rs;
        probs_out[(size_t)idx * LL + 1] = e1 * rs;
        probs_out[(size_t)idx * LL + 2] = e2 * rs;

        // loss: -log(clip(p_y, 1e-7, 1)) == min(logS - l_y, -log(1e-7))
        const float ly = (y == 0) ? l0 : ((y == 1) ? l1 : l2);
        loss += fminf(__logf(S) - ly, 16.11809565f);

        // accuracy: argmax(logits) == argmax(probs) (monotonic, same ties)
        int ap = 0; float pm = l0;
        if (l1 > pm) { ap = 1; pm = l1; }
        if (l2 > pm) { ap = 2; }
        corr += (ap == y) ? 1 : 0;
    }

    __shared__ float sl[4], sc[4];
    float ls = loss, cs = (float)corr;
#pragma unroll
    for (int off = 32; off > 0; off >>= 1) {
        ls += __shfl_down(ls, off, 64);
        cs += __shfl_down(cs, off, 64);
    }
    if ((threadIdx.x & 63) == 0) { sl[threadIdx.x >> 6] = ls; sc[threadIdx.x >> 6] = cs; }
    __syncthreads();
    if (threadIdx.x == 0) {
        ws[blockIdx.x]        = sl[0] + sl[1] + sl[2] + sl[3];
        ws[2048 + blockIdx.x] = sc[0] + sc[1] + sc[2] + sc[3];
    }
}

__global__ __launch_bounds__(256)
void finalize_kernel(const float* __restrict__ ws, float* __restrict__ out_tail)
{
    __shared__ float sl[4], sc[4];
    const int t = threadIdx.x;
    float ls = 0.0f, cs = 0.0f;
#pragma unroll
    for (int i = 0; i < 8; ++i) {
        ls += ws[t + 256 * i];
        cs += ws[2048 + t + 256 * i];
    }
#pragma unroll
    for (int off = 32; off > 0; off >>= 1) {
        ls += __shfl_down(ls, off, 64);
        cs += __shfl_down(cs, off, 64);
    }
    if ((t & 63) == 0) { sl[t >> 6] = ls; sc[t >> 6] = cs; }
    __syncthreads();
    if (t == 0) {
        const float L = sl[0] + sl[1] + sl[2] + sl[3];
        const float C = sc[0] + sc[1] + sc[2] + sc[3];
        const float inv = 1.0f / (float)((size_t)BB * TT);
        out_tail[0] = C * inv;   // accuracy
        out_tail[1] = L * inv;   // loss
    }
}

extern "C" void kernel_launch(void* const* d_in, const int* in_sizes, int n_in,
                              void* d_out, int out_size, void* d_ws, size_t ws_size,
                              hipStream_t stream)
{
    const int*   tok    = (const int*)  d_in[0];
    const float* labels = (const float*)d_in[1];
    // d_in[2] = mask (unused by reference math)
    const float* emb = (const float*)d_in[3];
    const float* W   = (const float*)d_in[4];
    const float* U   = (const float*)d_in[5];
    const float* bv  = (const float*)d_in[6];
    const float* Wo  = (const float*)d_in[7];
    const float* bo  = (const float*)d_in[8];

    float* out    = (float*)d_out;
    float* states = out;                                  // [B,T,10]
    float* probs  = out + (size_t)BB * TT * RR;           // [B,T,3]
    float* tail   = out + (size_t)BB * TT * (RR + LL);    // accuracy, loss
    float* ws     = (float*)d_ws;                         // 4096 floats used

    rnn_seq_kernel<<<512, 256, 0, stream>>>(tok, emb, W, U, bv, states);
    epilogue_kernel<<<2048, 256, 0, stream>>>(states, labels, Wo, bo, probs, ws);
    finalize_kernel<<<1, 256, 0, stream>>>(ws, tail);
}